// Round 9
// baseline (98.890 us; speedup 1.0000x reference)
//
#include <hip/hip_runtime.h>
#include <math.h>

constexpr int kH = 64, kW = 128, kB = 2, kS = 4;
constexpr int kNP = kH * kW;          // 8192 points per set
constexpr int kPairs = kB * kS;       // 8
constexpr int kDirs = kPairs * 2;     // 16
constexpr float kPen = 32768.0f;      // exclusion penalty (bf16-exact pow2)
constexpr float kPi = 3.14159265358979323846f;
constexpr float kFovUp = 3.0f * kPi / 180.0f;
constexpr float kFovDown = -25.0f * kPi / 180.0f;

typedef short short8 __attribute__((ext_vector_type(8)));
typedef unsigned short ushort8 __attribute__((ext_vector_type(8)));
typedef float floatx16 __attribute__((ext_vector_type(16)));

// R20: R19 post-mortem — correctness bug, not design. crec switched to
// consumer-dir indexing (crec[d] = candidates FOR dir d; prep writes rv
// points into crec[d1]) but nn still staged from crec[d^1] (the R18
// owner-dir convention), i.e. each dir matched against its own queries.
// Fix: nn stages from crec[d]. Everything else byte-identical to R19.
constexpr int NCC = 8;                // candidate chunks
constexpr int CCH = kNP / NCC;        // 1024 candidates per chunk
constexpr int NQB = 8;                // query blocks (8192/1024)
constexpr int QT = 4;                 // 32-query tiles per wave (128 q/wave)
constexpr int BT = 512;               // threads per block (8 waves)
// nn grid = 16 dirs * 8 * 8 = 1024 blocks = exactly 4 per CU

// ws layout (float offsets)
// crec   : [kDirs][kNP][16] ushort (tile layout) -> 4 MB @ 0
// qrec   : [kDirs][kNP][2][8] ushort (lo/hi)     -> 4 MB @ 1048576
// minpart: [kDirs][NCC][kNP] f32                 -> 4 MB @ 2097152
// wval   : [kDirs][kNP] f32                      -> 0.5 MB @ 3145728
// qpart  : [kDirs][NQB][2] f32 -> 256  @ 3276800
// mval   : [kDirs] f32         -> 16   @ 3277056
// dcnt   : [kDirs] u32         -> 16   @ 3277072
// acnt   : u32                 -> 1    @ 3277088
constexpr size_t OFF_QREC = 1048576;
constexpr size_t OFF_MINPART = 2097152;
constexpr size_t OFF_WVAL = 3145728;
constexpr size_t OFF_QPART = 3276800;
constexpr size_t OFF_MVAL = 3277056;
constexpr size_t OFF_DCNT = 3277072;
constexpr size_t OFF_ACNT = 3277088;

__device__ __forceinline__ unsigned short f2bf(float v) {
  unsigned u = __float_as_uint(v);
  unsigned r = u + 0x7FFFu + ((u >> 16) & 1u);   // RNE
  return (unsigned short)(r >> 16);
}
__device__ __forceinline__ float bf2f(unsigned short b) {
  return __uint_as_float(((unsigned)b) << 16);
}

// Candidate record F (16 bf16 K-slots, K=16 MFMA) with query record G:
//  k : 0    1    2    3    4    5    6    7  | 8    9    10   11   12-15
//  F : Xh   Xl   Xh   Yh   Yl   Yh   Zh   Zl | Zh   Ch   Cl   Cl2  0
//  G : xh   xh   xl   yh   yh   yl   zh   zh | zl   1    1    1    0
// sum_k F*G = X*x + Y*y + Z*z + ct  (drops only lo*lo terms ~2e-4)

// F-record of candidate point (x,y,z) with constant c, into a crec[d] base
// at point index kk. Tile layout: ctile (kk>>5) occupies 512 ushorts; lo8 of
// row (kk&31) at slot*8, hi8 at +256 ushorts. Matches nn's ds_read exactly.
__device__ __forceinline__ void write_F(unsigned short* base, int kk,
                                        float x, float y, float z, float c) {
  float X = -2.0f * x, Y = -2.0f * y, Z = -2.0f * z;
  unsigned short Xh = f2bf(X), Yh = f2bf(Y), Zh = f2bf(Z);
  unsigned short Xl = f2bf(X - bf2f(Xh));
  unsigned short Yl = f2bf(Y - bf2f(Yh));
  unsigned short Zl = f2bf(Z - bf2f(Zh));
  unsigned short Ch = f2bf(c);
  float c1 = c - bf2f(Ch);
  unsigned short Cl = f2bf(c1);
  unsigned short Cl2 = f2bf(c1 - bf2f(Cl));
  unsigned short* dst = base + (kk >> 5) * 512 + (kk & 31) * 8;
  *(ushort8*)dst = (ushort8){Xh, Xl, Xh, Yh, Yl, Yh, Zh, Zl};
  *(ushort8*)(dst + 256) = (ushort8){Zh, Ch, Cl, Cl2, 0, 0, 0, 0};
}

// G-record (query) of point (x,y,z): lo8 then hi8, 32 B per query.
__device__ __forceinline__ void write_G(unsigned short* dst,
                                        float x, float y, float z) {
  const unsigned short one_bf = 0x3F80;
  unsigned short xh = f2bf(x), yh = f2bf(y), zh = f2bf(z);
  unsigned short xl = f2bf(x - bf2f(xh));
  unsigned short yl = f2bf(y - bf2f(yh));
  unsigned short zl = f2bf(z - bf2f(zh));
  *(ushort8*)dst = (ushort8){xh, xh, xl, yh, yh, yl, zh, zh};
  *(ushort8*)(dst + 8) = (ushort8){zl, one_bf, one_bf, one_bf, 0, 0, 0, 0};
}

__global__ __launch_bounds__(256) void prep_kernel(
    const float* __restrict__ rv, const float* __restrict__ tgt,
    unsigned short* __restrict__ crec, unsigned short* __restrict__ qrec,
    float* __restrict__ wval, float* __restrict__ mval,
    unsigned* __restrict__ dcnt, unsigned* __restrict__ acnt) {
  int idx = blockIdx.x * 256 + threadIdx.x;   // [0, kPairs*kNP)
  int p = idx >> 13;
  int k = idx & (kNP - 1);
  int h = k >> 7;
  int w = k & 127;

  float r = rv[idx];
  float pitch = (1.0f - (h + 0.5f) * (1.0f / kH)) * (kFovUp - kFovDown) + kFovDown;
  float yaw = -(((w + 0.5f) * (1.0f / kW)) * 2.0f - 1.0f) * kPi;
  float cp = __cosf(pitch), sp = __sinf(pitch);
  float cy = __cosf(yaw), sy = __sinf(yaw);
  float px = r * cp * cy, py = r * cp * sy, pz = r * sp;
  float mo = (r > 0.0f) ? 1.0f : 0.0f;

  const float* tb = tgt + (size_t)p * 4 * kNP;
  float mt = (tb[k] > 0.0f) ? 1.0f : 0.0f;
  float tx = tb[kNP + k], ty = tb[2 * kNP + k], tz = tb[3 * kNP + k];

  float no = px * px + py * py + pz * pz;
  float nt = tx * tx + ty * ty + tz * tz;
  float co = no + kPen * (1.0f - mo);
  float ct = nt + kPen * (1.0f - mt);

  int d0 = 2 * p, d1 = d0 + 1;
  // wval[d][k] < 16384 <=> valid query; equals |q|^2 then.
  wval[(size_t)d0 * kNP + k] = co;
  wval[(size_t)d1 * kNP + k] = ct;

  // crec[d] = candidates FOR dir d = points of dir d^1:
  // rv point -> candidate set of d1; tgt point -> candidate set of d0.
  write_F(crec + (size_t)d1 * kNP * 16, k, px, py, pz, co);
  write_F(crec + (size_t)d0 * kNP * 16, k, tx, ty, tz, ct);
  // qrec[d] = query records of dir d's own points.
  write_G(qrec + ((size_t)d0 * kNP + k) * 16, px, py, pz);
  write_G(qrec + ((size_t)d1 * kNP + k) * 16, tx, ty, tz);

  if (idx < kDirs) { dcnt[idx] = 0u; mval[idx] = 0.0f; }
  if (idx == kDirs) *acnt = 0u;
  // minpart needs no init: every (d,ch,q) slot is written each launch.
}

__global__ __launch_bounds__(BT) void nn_kernel(
    const unsigned short* __restrict__ crec,
    const unsigned short* __restrict__ qrec, float* __restrict__ minpart) {
  // 32 KB candidate records: 32 ctiles of 1 KB = [32 rows x 8 lo][32 rows x 8 hi]
  // +1 KB slack so the loop's A-prefetch may harmlessly overread one tile.
  __shared__ __align__(16) unsigned short sc[CCH * 16 + 512];

  int bid = blockIdx.x;
  int d = bid >> 6;            // 64 blocks per dir
  int qb = (bid >> 3) & 7;
  int ch = bid & 7;
  int t = threadIdx.x;

  // ---- stage: LINEAR 32 KB copy. crec[d] is already the candidate set of
  // dir d in LDS tile layout (R20 fix: index by d, NOT d^1). ----
  const uint4* src = (const uint4*)(crec + ((size_t)d * kNP + ch * CCH) * 16);
  uint4* dstv = (uint4*)sc;
#pragma unroll
  for (int i = 0; i < 4; ++i) {
    int j = t + i * BT;
    dstv[j] = src[j];
  }
  __syncthreads();

  int wave = t >> 6, lane = t & 63;
  int col = lane & 31, half = lane >> 5;   // B: col = lane&31 (HW-verified)
  int qgl = d * kNP + qb * 1024 + wave * 128;   // global query base

  const short8* qr = (const short8*)qrec;
  short8 bq[QT];
  float mn[QT];
#pragma unroll
  for (int qt = 0; qt < QT; ++qt) {
    bq[qt] = qr[(size_t)(qgl + qt * 32 + col) * 2 + half];
    mn[qt] = 3.0e38f;
  }

  floatx16 zc = {0.0f, 0.0f, 0.0f, 0.0f, 0.0f, 0.0f, 0.0f, 0.0f,
                 0.0f, 0.0f, 0.0f, 0.0f, 0.0f, 0.0f, 0.0f, 0.0f};

  // A fragment: lane l holds row l&31, K-half l>>5 -> linear offset l*16 B.
  const short8* ap = (const short8*)sc + lane;   // stride 64 short8s per ctile
  short8 a = ap[0];
#pragma unroll 2
  for (int ctile = 0; ctile < CCH / 32; ++ctile) {
    short8 an = ap[(ctile + 1) * 64];   // prefetch next tile (slack covers last)
#pragma unroll
    for (int qt = 0; qt < QT; ++qt) {
      floatx16 dr =
          __builtin_amdgcn_mfma_f32_32x32x16_bf16(a, bq[qt], zc, 0, 0, 0);
      // 16->1 row-min fold, min3-shaped (compiler emits ~8 v_min3)
      float f0 = fminf(fminf(dr[0], dr[1]), dr[2]);
      float f1 = fminf(fminf(dr[3], dr[4]), dr[5]);
      float f2 = fminf(fminf(dr[6], dr[7]), dr[8]);
      float f3 = fminf(fminf(dr[9], dr[10]), dr[11]);
      float f4 = fminf(fminf(dr[12], dr[13]), dr[14]);
      float g0 = fminf(fminf(f0, f1), dr[15]);
      float g1 = fminf(fminf(f2, f3), f4);
      mn[qt] = fminf(fminf(g0, g1), mn[qt]);
    }
    a = an;
  }

  // ---- publish per-chunk partial mins: PLAIN stores, one writer per slot.
  // Cross-kernel visibility handled at the dispatch boundary. No tail.
#pragma unroll
  for (int qt = 0; qt < QT; ++qt) {
    float m = fminf(mn[qt], __shfl_xor(mn[qt], 32));
    if (lane < 32)
      minpart[(size_t)(d * NCC + ch) * kNP + qb * 1024 + wave * 128 +
              qt * 32 + lane] = m;
  }
}

__global__ __launch_bounds__(BT) void reduce_kernel(
    const float* __restrict__ wval, const float* __restrict__ minpart,
    float* __restrict__ qpart, float* __restrict__ mval,
    unsigned* __restrict__ dcnt, unsigned* __restrict__ acnt,
    float* __restrict__ out) {
  __shared__ unsigned s_ticket;
  __shared__ float sw[8], sm[8];

  int d = blockIdx.x >> 3;     // 8 blocks per dir
  int qb = blockIdx.x & 7;
  int t = threadIdx.x;

  float wsum = 0.0f, msum = 0.0f;
#pragma unroll
  for (int r = 0; r < 1024 / BT; ++r) {     // 2 rows of 512 queries
    int q = qb * 1024 + r * BT + t;         // dir-local query index
    float mv = 3.0e38f;
#pragma unroll
    for (int c = 0; c < NCC; ++c)
      mv = fminf(mv, minpart[(size_t)(d * NCC + c) * kNP + q]);
    float w = wval[(size_t)d * kNP + q];
    if (w < 16384.0f) {
      wsum += w + mv;
      msum += 1.0f;
    }
  }
#pragma unroll
  for (int off = 32; off; off >>= 1) {
    wsum += __shfl_down(wsum, off);
    msum += __shfl_down(msum, off);
  }
  if ((t & 63) == 0) { sw[t >> 6] = wsum; sm[t >> 6] = msum; }
  __syncthreads();
  if (t == 0) {
    float ws_ = 0.0f, ms_ = 0.0f;
#pragma unroll
    for (int w2 = 0; w2 < 8; ++w2) { ws_ += sw[w2]; ms_ += sm[w2]; }
    int g = d * NQB + qb;
    __hip_atomic_store(&qpart[g * 2], ws_, __ATOMIC_RELAXED,
                       __HIP_MEMORY_SCOPE_AGENT);
    __hip_atomic_store(&qpart[g * 2 + 1], ms_, __ATOMIC_RELAXED,
                       __HIP_MEMORY_SCOPE_AGENT);
    // RELEASE publishes the qpart stores (waitcnt only, no L2 flush — the
    // proven R11/R16 pattern). Only 128+16+1 RMWs total in this kernel.
    s_ticket = __hip_atomic_fetch_add(&dcnt[d], 1u, __ATOMIC_ACQ_REL,
                                      __HIP_MEMORY_SCOPE_AGENT);
  }
  __syncthreads();
  if (s_ticket != (unsigned)(NQB - 1)) return;

  // ---- last block of this dir sums the 8 partial pairs (fixed order) ----
  if (t == 0) {
    float W = 0.0f, M = 0.0f;
#pragma unroll
    for (int g = 0; g < NQB; ++g) {
      W += __uint_as_float(__hip_atomic_load(
          (unsigned*)&qpart[(d * NQB + g) * 2], __ATOMIC_RELAXED,
          __HIP_MEMORY_SCOPE_AGENT));
      M += __uint_as_float(__hip_atomic_load(
          (unsigned*)&qpart[(d * NQB + g) * 2 + 1], __ATOMIC_RELAXED,
          __HIP_MEMORY_SCOPE_AGENT));
    }
    __hip_atomic_store(&mval[d], W / fmaxf(M, 1.0f), __ATOMIC_RELAXED,
                       __HIP_MEMORY_SCOPE_AGENT);
    s_ticket = __hip_atomic_fetch_add(acnt, 1u, __ATOMIC_ACQ_REL,
                                      __HIP_MEMORY_SCOPE_AGENT);
  }
  __syncthreads();
  if (s_ticket != (unsigned)(kDirs - 1)) return;
  // ---- very last block combines 16 dir values into the 12 outputs ----
  if (t == 0) {
    float mv[kDirs];
    for (int dd = 0; dd < kDirs; ++dd)
      mv[dd] = __hip_atomic_load(&mval[dd], __ATOMIC_RELAXED,
                                 __HIP_MEMORY_SCOPE_AGENT);
    for (int s = 0; s < kS; ++s) {
      float acc = 0.0f;
      for (int b = 0; b < kB; ++b) {
        int p = b * kS + s;
        float tens = mv[2 * p] + mv[2 * p + 1];
        out[kS + s * kB + b] = tens;
        acc += tens;
      }
      out[s] = acc * (1.0f / kB);
    }
  }
}

extern "C" void kernel_launch(void* const* d_in, const int* in_sizes, int n_in,
                              void* d_out, int out_size, void* d_ws, size_t ws_size,
                              hipStream_t stream) {
  const float* rv = (const float*)d_in[0];
  const float* tgt = (const float*)d_in[1];
  float* ws = (float*)d_ws;
  unsigned short* crec = (unsigned short*)ws;
  unsigned short* qrec = (unsigned short*)(ws + OFF_QREC);
  float* minpart = ws + OFF_MINPART;
  float* wval = ws + OFF_WVAL;
  float* qpart = ws + OFF_QPART;
  float* mval = ws + OFF_MVAL;
  unsigned* dcnt = (unsigned*)(ws + OFF_DCNT);
  unsigned* acnt = (unsigned*)(ws + OFF_ACNT);
  float* out = (float*)d_out;

  hipLaunchKernelGGL(prep_kernel, dim3(kPairs * kNP / 256), dim3(256), 0, stream,
                     rv, tgt, crec, qrec, wval, mval, dcnt, acnt);
  hipLaunchKernelGGL(nn_kernel, dim3(kDirs * NQB * NCC), dim3(BT), 0, stream,
                     crec, qrec, minpart);
  hipLaunchKernelGGL(reduce_kernel, dim3(kDirs * NQB), dim3(BT), 0, stream,
                     wval, minpart, qpart, mval, dcnt, acnt, out);
}